// Round 11
// baseline (85.415 us; speedup 1.0000x reference)
//
#include <hip/hip_runtime.h>
#include <hip/hip_bf16.h>
#include <cstdint>

typedef float f32x4 __attribute__((ext_vector_type(4)));
typedef short bf16x8 __attribute__((ext_vector_type(8)));

#define P_TOT 8192      // B*L
#define KH 768          // K*H (GEMM K-dim)
#define PADL 258        // padded sequence length (zero row before & after)
#define EPS_ 1e-5f

__device__ __forceinline__ unsigned short f2bf(float f) {
    unsigned int x = __float_as_uint(f);
    unsigned int r = (x + 0x7fffu + ((x >> 16) & 1u)) >> 16;
    return (unsigned short)r;
}

// ================= fused pre-kernel: embed x4 (2048) | wtrans (288) | cumsum (32) =================
__global__ __launch_bounds__(256) void k_pre(
        const float* __restrict__ x, const float* __restrict__ pt, const float* __restrict__ et,
        const float* __restrict__ pbins, const float* __restrict__ ebins,
        const float* __restrict__ pemb, const float* __restrict__ eemb,
        const float* __restrict__ w1, const float* __restrict__ w2,
        const int* __restrict__ dur,
        unsigned short* __restrict__ xplain, unsigned short* __restrict__ xpplain,
        float* __restrict__ xpe, unsigned short* __restrict__ bt,
        int* __restrict__ cum, float* __restrict__ mel_len_out) {
    __shared__ char smem[16640];
    const int bx = blockIdx.x;
    const int t = threadIdx.x;

    if (bx < 2048) {
        float* pb = (float*)smem;
        float* eb = pb + 256;
        if (t < 255) { pb[t] = pbins[t]; eb[t] = ebins[t]; }
        __syncthreads();
        int w = t >> 6, lane = t & 63;
        int p = bx * 4 + w; int b = p >> 8; int l = p & 255;
        float ptv = pt[p], etv = et[p];
        int lo = 0, hi = 255;
        while (lo < hi) { int mid = (lo + hi) >> 1; if (pb[mid] < ptv) lo = mid + 1; else hi = mid; }
        int pidx = lo;
        lo = 0; hi = 255;
        while (lo < hi) { int mid = (lo + hi) >> 1; if (eb[mid] < etv) lo = mid + 1; else hi = mid; }
        int eidx = lo;
        f32x4 xv = *(const f32x4*)(x    + (size_t)p * 256 + lane * 4);
        f32x4 pe = *(const f32x4*)(pemb + (size_t)pidx * 256 + lane * 4);
        f32x4 ee = *(const f32x4*)(eemb + (size_t)eidx * 256 + lane * 4);
        f32x4 xpv = xv + pe;
        f32x4 xpev = xpv + ee;
        *(f32x4*)(xpe + (size_t)p * 256 + lane * 4) = xpev;
        size_t row = (size_t)b * PADL + 1 + l;
        ushort4 xb, xpb;
        xb.x = f2bf(xv[0]);  xb.y = f2bf(xv[1]);  xb.z = f2bf(xv[2]);  xb.w = f2bf(xv[3]);
        xpb.x = f2bf(xpv[0]); xpb.y = f2bf(xpv[1]); xpb.z = f2bf(xpv[2]); xpb.w = f2bf(xpv[3]);
        *(ushort4*)(xplain  + row * 256 + lane * 4) = xb;
        *(ushort4*)(xpplain + row * 256 + lane * 4) = xpb;
        ushort4 z; z.x = z.y = z.z = z.w = 0;
        if (l == 0) {
            *(ushort4*)(xplain  + ((size_t)b * PADL) * 256 + lane * 4) = z;
            *(ushort4*)(xpplain + ((size_t)b * PADL) * 256 + lane * 4) = z;
        }
        if (l == 255) {
            *(ushort4*)(xplain  + ((size_t)b * PADL + 257) * 256 + lane * 4) = z;
            *(ushort4*)(xpplain + ((size_t)b * PADL + 257) * 256 + lane * 4) = z;
        }
    } else if (bx < 2336) {
        float (*tile)[65] = (float(*)[65])smem;
        int id = bx - 2048;
        int tf = id & 3; int th = (id >> 2) & 3;
        int rest = id >> 4;
        int k = rest % 3; rest /= 3;
        int set = rest % 3; int tensor = rest / 3;
        const float* src = tensor ? w2 : w1;
        const float* s = src + (((size_t)set * 3 + k) * 256 + th * 64) * 256 + tf * 64;
        int fl = t & 63;
        int q = t >> 6;
#pragma unroll
        for (int i = 0; i < 16; ++i) {
            int hl = i * 4 + q;
            tile[hl][fl] = s[(size_t)hl * 256 + fl];
        }
        __syncthreads();
        size_t rowbase = (size_t)tensor * 768 + set * 256 + tf * 64;
        size_t colbase = (size_t)k * 256 + th * 64;
#pragma unroll
        for (int i = 0; i < 16; ++i) {
            int f2 = i * 4 + q;
            bt[(rowbase + f2) * KH + colbase + fl] = f2bf(tile[fl][f2]);
        }
    } else {
        int* sh = (int*)smem;
        int b = bx - 2336;
        int l = t;
        sh[l] = dur[b * 256 + l];
        for (int s = 1; s < 256; s <<= 1) {
            __syncthreads();
            int add = (l >= s) ? sh[l - s] : 0;
            __syncthreads();
            sh[l] += add;
        }
        __syncthreads();
        cum[b * 256 + l] = sh[l];
        if (l == 0) mel_len_out[b] = (float)sh[255];
    }
}

// ================= conv GEMM: 128x256 tile, 512 threads, BK=64; A staged ONCE; B dbuf =================
// A-LDS: 130 rows x 512B; phys byte = r*512 + (c ^ ((r&7)<<4)); pre-swizzled global src.
// B-LDS (BK=64): 256 rows x 128B; phys byte = c*128 + (kb ^ ((c&7)<<4)).
__device__ __forceinline__ void stageA128(const unsigned short* __restrict__ A, int browPad,
                                          unsigned short* As, int tid) {
    for (int g = tid; g < 4160; g += 512) {
        int p = g * 16;
        int r = p >> 9;
        int c = (p & 511) ^ ((r & 7) << 4);
        __builtin_amdgcn_global_load_lds(
            (const __attribute__((address_space(1))) unsigned int*)((const char*)(A + (size_t)(browPad + r) * 256) + c),
            (__attribute__((address_space(3))) unsigned int*)((char*)As + p), 16, 0, 0);
    }
}

__device__ __forceinline__ void stageB64(const unsigned short* __restrict__ Bm, int kt,
                                         unsigned short* Bs, int tid) {
#pragma unroll
    for (int j = 0; j < 4; ++j) {
        int p = j * 8192 + tid * 16;           // physical byte 0..32767
        int c = p >> 7;                        // B row (output col) 0..255
        int kb = (p & 127) ^ ((c & 7) << 4);   // logical k-byte within 128B chunk
        __builtin_amdgcn_global_load_lds(
            (const __attribute__((address_space(1))) unsigned int*)((const char*)(Bm + (size_t)c * KH + kt) + kb),
            (__attribute__((address_space(3))) unsigned int*)((char*)Bs + p), 16, 0, 0);
    }
}

__device__ __forceinline__ void compute128_64(const unsigned short* As, const unsigned short* Bs,
                                              int ktAbs, int lane, int wr, int wc, f32x4 acc[4][4]) {
    const int rsel = lane & 15;
    const int lhi = lane >> 4;
#pragma unroll
    for (int s = 0; s < 2; ++s) {
        const int k = ktAbs + s * 32;
        const int tap = k >> 8;
        const int hcb = (k & 255) * 2 + lhi * 16;      // logical byte within A row
        const int bofs = s * 64 + lhi * 16;            // logical byte within B 128B chunk
        bf16x8 af[4], bfr[4];
#pragma unroll
        for (int m = 0; m < 4; ++m) {
            int r = tap + wr * 64 + m * 16 + rsel;
            af[m] = *(const bf16x8*)((const char*)As + r * 512 + (hcb ^ ((r & 7) << 4)));
        }
#pragma unroll
        for (int n = 0; n < 4; ++n) {
            int c = wc * 64 + n * 16 + rsel;
            bfr[n] = *(const bf16x8*)((const char*)Bs + c * 128 + (bofs ^ ((c & 7) << 4)));
        }
#pragma unroll
        for (int m = 0; m < 4; ++m)
#pragma unroll
            for (int n = 0; n < 4; ++n)
                acc[m][n] = __builtin_amdgcn_mfma_f32_16x16x32_bf16(af[m], bfr[n], acc[m][n], 0, 0, 0);
    }
}

// ================= conv1 + bias + relu + LN -> padded bf16 h =================
__global__ __launch_bounds__(512) void k_conv_ln1(
        const unsigned short* __restrict__ xplain, const unsigned short* __restrict__ xpplain,
        const unsigned short* __restrict__ bt,
        const float* __restrict__ b1, const float* __restrict__ g1, const float* __restrict__ be1,
        unsigned short* __restrict__ h0, unsigned short* __restrict__ h1, unsigned short* __restrict__ h2) {
    __shared__ unsigned short As[33280];     // 130 rows x 512B, swizzled
    __shared__ unsigned short Bs[2][16384];  // 256 x 128B, swizzled, dbuf
    __shared__ float2 red[4][128];

    const int pred = blockIdx.y;
    const unsigned short* A  = (pred < 2) ? xplain : xpplain;
    const unsigned short* Bm = bt + (size_t)pred * 256 * KH;
    unsigned short* hout = (pred == 0) ? h0 : (pred == 1) ? h1 : h2;

    const int rowBase = blockIdx.x * 128;
    const int bb = rowBase >> 8;
    const int l0 = rowBase & 255;
    const int browPad = bb * PADL + l0;
    const int tid = threadIdx.x;
    const int lane = tid & 63;
    const int wv = tid >> 6;
    const int wr = wv >> 2, wc = wv & 3;
    const int rsel = lane & 15;
    const int lhi = lane >> 4;

    f32x4 acc[4][4];
#pragma unroll
    for (int m = 0; m < 4; ++m)
#pragma unroll
        for (int n = 0; n < 4; ++n) acc[m][n] = (f32x4){0.f, 0.f, 0.f, 0.f};

    stageA128(A, browPad, As, tid);
    stageB64(Bm, 0, Bs[0], tid);
    __syncthreads();
    int cur = 0;
    for (int kt = 64; kt < KH; kt += 64) {
        stageB64(Bm, kt, Bs[cur ^ 1], tid);
        compute128_64(As, Bs[cur], kt - 64, lane, wr, wc, acc);
        __syncthreads();
        cur ^= 1;
    }
    compute128_64(As, Bs[cur], KH - 64, lane, wr, wc, acc);

    float bcol[4], gcol[4], becol[4];
#pragma unroll
    for (int n = 0; n < 4; ++n) {
        int c = wc * 64 + n * 16 + rsel;
        bcol[n] = b1[pred * 256 + c];
        gcol[n] = g1[pred * 256 + c];
        becol[n] = be1[pred * 256 + c];
    }

#pragma unroll
    for (int m = 0; m < 4; ++m)
#pragma unroll
        for (int r = 0; r < 4; ++r) {
            float s = 0.f, s2 = 0.f;
#pragma unroll
            for (int n = 0; n < 4; ++n) {
                float v = fmaxf(acc[m][n][r] + bcol[n], 0.f);
                s += v; s2 += v * v;
            }
#pragma unroll
            for (int o = 1; o < 16; o <<= 1) { s += __shfl_xor(s, o); s2 += __shfl_xor(s2, o); }
            if (rsel == 0) red[wc][wr * 64 + m * 16 + lhi * 4 + r] = make_float2(s, s2);
        }
    __syncthreads();
    if (tid < 128) {
        float2 a0 = red[0][tid], a1 = red[1][tid], a2 = red[2][tid], a3 = red[3][tid];
        red[0][tid] = make_float2(a0.x + a1.x + a2.x + a3.x, a0.y + a1.y + a2.y + a3.y);
    }
    __syncthreads();

#pragma unroll
    for (int m = 0; m < 4; ++m)
#pragma unroll
        for (int r = 0; r < 4; ++r) {
            int rl = wr * 64 + m * 16 + lhi * 4 + r;
            float2 t = red[0][rl];
            float mean = t.x * (1.f / 256.f);
            float var = t.y * (1.f / 256.f) - mean * mean;
            float inv = rsqrtf(var + EPS_);
            int l = l0 + rl;
            size_t row = (size_t)bb * PADL + 1 + l;
#pragma unroll
            for (int n = 0; n < 4; ++n) {
                float v = fmaxf(acc[m][n][r] + bcol[n], 0.f);
                float h = (v - mean) * inv * gcol[n] + becol[n];
                int c = wc * 64 + n * 16 + rsel;
                hout[row * 256 + c] = f2bf(h);
                if (l == 0)   hout[((size_t)bb * PADL) * 256 + c] = 0;
                if (l == 255) hout[((size_t)bb * PADL + 257) * 256 + c] = 0;
            }
        }
}

// ===== fused: conv2+LN+proj (blocks 0..191) | gather (blocks 192..2239), 512 threads =====
__global__ __launch_bounds__(512) void k_conv2_gather(
        const unsigned short* __restrict__ h0, const unsigned short* __restrict__ h1,
        const unsigned short* __restrict__ h2, const unsigned short* __restrict__ bt,
        const float* __restrict__ b2, const float* __restrict__ g2, const float* __restrict__ be2,
        const float* __restrict__ wl, const float* __restrict__ bl,
        const char* __restrict__ mask,
        const float* __restrict__ xpe, const int* __restrict__ cum,
        float* __restrict__ outp, float* __restrict__ out, float* __restrict__ maskout) {
    __shared__ unsigned short As[33280];
    __shared__ unsigned short Bs[2][16384];
    __shared__ float2 red[4][128];
    __shared__ float  red2[4][128];

    const int bx = blockIdx.x;
    const int tid = threadIdx.x;

    if (bx < 192) {
        // ---- conv2 role ----
        const int pred = bx >> 6;
        const int px = bx & 63;
        const unsigned short* A  = (pred == 0) ? h0 : (pred == 1) ? h1 : h2;
        const unsigned short* Bm = bt + (size_t)(768 + pred * 256) * KH;

        const int rowBase = px * 128;
        const int bb = rowBase >> 8;
        const int l0 = rowBase & 255;
        const int browPad = bb * PADL + l0;
        const int lane = tid & 63;
        const int wv = tid >> 6;
        const int wr = wv >> 2, wc = wv & 3;
        const int rsel = lane & 15;
        const int lhi = lane >> 4;

        f32x4 acc[4][4];
#pragma unroll
        for (int m = 0; m < 4; ++m)
#pragma unroll
            for (int n = 0; n < 4; ++n) acc[m][n] = (f32x4){0.f, 0.f, 0.f, 0.f};

        stageA128(A, browPad, As, tid);
        stageB64(Bm, 0, Bs[0], tid);
        __syncthreads();
        int cur = 0;
        for (int kt = 64; kt < KH; kt += 64) {
            stageB64(Bm, kt, Bs[cur ^ 1], tid);
            compute128_64(As, Bs[cur], kt - 64, lane, wr, wc, acc);
            __syncthreads();
            cur ^= 1;
        }
        compute128_64(As, Bs[cur], KH - 64, lane, wr, wc, acc);

        float bcol[4], gcol[4], becol[4], wcol[4];
#pragma unroll
        for (int n = 0; n < 4; ++n) {
            int c = wc * 64 + n * 16 + rsel;
            bcol[n] = b2[pred * 256 + c];
            gcol[n] = g2[pred * 256 + c];
            becol[n] = be2[pred * 256 + c];
            wcol[n] = wl[pred * 256 + c];
        }

#pragma unroll
        for (int m = 0; m < 4; ++m)
#pragma unroll
            for (int r = 0; r < 4; ++r) {
                float s = 0.f, s2 = 0.f;
#pragma unroll
                for (int n = 0; n < 4; ++n) {
                    float v = fmaxf(acc[m][n][r] + bcol[n], 0.f);
                    s += v; s2 += v * v;
                }
#pragma unroll
                for (int o = 1; o < 16; o <<= 1) { s += __shfl_xor(s, o); s2 += __shfl_xor(s2, o); }
                if (rsel == 0) red[wc][wr * 64 + m * 16 + lhi * 4 + r] = make_float2(s, s2);
            }
        __syncthreads();
        if (tid < 128) {
            float2 a0 = red[0][tid], a1 = red[1][tid], a2 = red[2][tid], a3 = red[3][tid];
            red[0][tid] = make_float2(a0.x + a1.x + a2.x + a3.x, a0.y + a1.y + a2.y + a3.y);
        }
        __syncthreads();

#pragma unroll
        for (int m = 0; m < 4; ++m)
#pragma unroll
            for (int r = 0; r < 4; ++r) {
                int rl = wr * 64 + m * 16 + lhi * 4 + r;
                float2 t = red[0][rl];
                float mean = t.x * (1.f / 256.f);
                float var = t.y * (1.f / 256.f) - mean * mean;
                float inv = rsqrtf(var + EPS_);
                float d = 0.f;
#pragma unroll
                for (int n = 0; n < 4; ++n) {
                    float v = fmaxf(acc[m][n][r] + bcol[n], 0.f);
                    float h = (v - mean) * inv * gcol[n] + becol[n];
                    d += h * wcol[n];
                }
#pragma unroll
                for (int o = 1; o < 16; o <<= 1) d += __shfl_xor(d, o);
                if (rsel == 0) red2[wc][rl] = d;
            }
        __syncthreads();
        if (tid < 128) {
            int p = rowBase + tid;
            float o = red2[0][tid] + red2[1][tid] + red2[2][tid] + red2[3][tid] + bl[pred];
            if (mask[p]) o = 0.f;
            outp[(size_t)pred * P_TOT + p] = o;
        }
    } else {
        // ---- gather role: 2048 blocks, 32 mel rows each, 8 waves ----
        int* sc = (int*)As;
        int g = bx - 192;
        int b = g >> 6;
        int t0 = (g & 63) * 32;
        if (tid < 256) sc[tid] = cum[b * 256 + tid];
        __syncthreads();
        int mel = sc[255];
        int w = tid >> 6, lane = tid & 63;
#pragma unroll
        for (int it = 0; it < 4; ++it) {
            int t = t0 + it * 8 + w;
            int lo = 0, hi = 256;
            while (lo < hi) { int mid = (lo + hi) >> 1; if (sc[mid] <= t) lo = mid + 1; else hi = mid; }
            bool valid = t < mel;
            int idx = lo > 255 ? 255 : lo;
            f32x4 v = (f32x4){0.f, 0.f, 0.f, 0.f};
            if (valid) v = *(const f32x4*)(xpe + ((size_t)(b * 256 + idx)) * 256 + lane * 4);
            *(f32x4*)(out + ((size_t)(b * 2048 + t)) * 256 + lane * 4) = v;
            if (lane == 0) maskout[b * 2048 + t] = valid ? 0.f : 1.f;
        }
    }
}

extern "C" void kernel_launch(void* const* d_in, const int* in_sizes, int n_in,
                              void* d_out, int out_size, void* d_ws, size_t ws_size,
                              hipStream_t stream) {
    const float* x     = (const float*)d_in[0];
    const float* pt    = (const float*)d_in[1];
    const float* et    = (const float*)d_in[2];
    const float* w1    = (const float*)d_in[3];
    const float* b1    = (const float*)d_in[4];
    const float* g1    = (const float*)d_in[5];
    const float* be1   = (const float*)d_in[6];
    const float* w2    = (const float*)d_in[7];
    const float* b2    = (const float*)d_in[8];
    const float* g2    = (const float*)d_in[9];
    const float* be2   = (const float*)d_in[10];
    const float* wl    = (const float*)d_in[11];
    const float* bl    = (const float*)d_in[12];
    const float* pbins = (const float*)d_in[13];
    const float* ebins = (const float*)d_in[14];
    const float* pemb  = (const float*)d_in[15];
    const float* eemb  = (const float*)d_in[16];
    const char*  mask  = (const char*)d_in[17];
    const int*   dur   = (const int*)d_in[18];

    char* ws = (char*)d_ws;
    unsigned short* xplain  = (unsigned short*)(ws + 0);
    unsigned short* xpplain = (unsigned short*)(ws + 8388608);
    unsigned short* h0      = (unsigned short*)(ws + 16777216);
    unsigned short* h1      = (unsigned short*)(ws + 25165824);
    unsigned short* h2      = (unsigned short*)(ws + 33554432);
    float*          xpe     = (float*)(ws + 41943040);
    unsigned short* btall   = (unsigned short*)(ws + 52428800);
    int*            cum     = (int*)(ws + 56623104);

    float* out        = (float*)d_out;
    float* out_pred   = out + 16777216;           // log_dur | pitch | energy (8192 each)
    float* out_mellen = out + 16801792;
    float* out_mask   = out + 16801824;

    hipLaunchKernelGGL(k_pre, dim3(2368), dim3(256), 0, stream,
                       x, pt, et, pbins, ebins, pemb, eemb, w1, w2, dur,
                       xplain, xpplain, xpe, btall, cum, out_mellen);

    hipLaunchKernelGGL(k_conv_ln1, dim3(64, 3), dim3(512), 0, stream,
                       xplain, xpplain, btall, b1, g1, be1, h0, h1, h2);

    hipLaunchKernelGGL(k_conv2_gather, dim3(2240), dim3(512), 0, stream,
                       h0, h1, h2, btall, b2, g2, be2, wl, bl, mask,
                       xpe, cum, out_pred, out, out_mask);
}

// Round 12
// 73.872 us; speedup vs baseline: 1.1563x; 1.1563x over previous
//
#include <hip/hip_runtime.h>
#include <hip/hip_bf16.h>
#include <cstdint>

typedef float f32x4 __attribute__((ext_vector_type(4)));
typedef short bf16x8 __attribute__((ext_vector_type(8)));

#define P_TOT 8192      // B*L
#define KH 768          // K*H (GEMM K-dim)
#define PADL 258        // padded sequence length (zero row before & after)
#define EPS_ 1e-5f

__device__ __forceinline__ unsigned short f2bf(float f) {
    unsigned int x = __float_as_uint(f);
    unsigned int r = (x + 0x7fffu + ((x >> 16) & 1u)) >> 16;
    return (unsigned short)r;
}

// ==== fused pre-kernel: embed+scatter (2048) | wtrans (288) | mel_len (32) | zero-fill (2048) ====
__global__ __launch_bounds__(256) void k_pre(
        const float* __restrict__ x, const float* __restrict__ pt, const float* __restrict__ et,
        const float* __restrict__ pbins, const float* __restrict__ ebins,
        const float* __restrict__ pemb, const float* __restrict__ eemb,
        const float* __restrict__ w1, const float* __restrict__ w2,
        const int* __restrict__ dur,
        unsigned short* __restrict__ xplain, unsigned short* __restrict__ xpplain,
        unsigned short* __restrict__ bt,
        float* __restrict__ out, float* __restrict__ maskout, float* __restrict__ mel_len_out) {
    __shared__ char smem[16640];
    const int bx = blockIdx.x;
    const int t = threadIdx.x;

    if (bx < 2048) {
        // ---- embed + length-regulate scatter role: 4 rows of one batch per block ----
        float* pb = (float*)smem;              // 256 f
        float* eb = pb + 256;                  // 256 f
        int*   sc = (int*)(eb + 256);          // 256 i (inclusive cumsum)
        const int b = bx >> 6;                 // batch (4 rows/block, 64 blocks/batch)
        if (t < 255) { pb[t] = pbins[t]; eb[t] = ebins[t]; }
        sc[t] = dur[b * 256 + t];
        for (int s = 1; s < 256; s <<= 1) {
            __syncthreads();
            int add = (t >= s) ? sc[t - s] : 0;
            __syncthreads();
            sc[t] += add;
        }
        __syncthreads();

        int w = t >> 6, lane = t & 63;
        int p = bx * 4 + w; int l = p & 255;
        float ptv = pt[p], etv = et[p];
        int lo = 0, hi = 255;
        while (lo < hi) { int mid = (lo + hi) >> 1; if (pb[mid] < ptv) lo = mid + 1; else hi = mid; }
        int pidx = lo;
        lo = 0; hi = 255;
        while (lo < hi) { int mid = (lo + hi) >> 1; if (eb[mid] < etv) lo = mid + 1; else hi = mid; }
        int eidx = lo;
        f32x4 xv = *(const f32x4*)(x    + (size_t)p * 256 + lane * 4);
        f32x4 pe = *(const f32x4*)(pemb + (size_t)pidx * 256 + lane * 4);
        f32x4 ee = *(const f32x4*)(eemb + (size_t)eidx * 256 + lane * 4);
        f32x4 xpv = xv + pe;
        f32x4 xpev = xpv + ee;
        size_t row = (size_t)b * PADL + 1 + l;
        ushort4 xb, xpb;
        xb.x = f2bf(xv[0]);  xb.y = f2bf(xv[1]);  xb.z = f2bf(xv[2]);  xb.w = f2bf(xv[3]);
        xpb.x = f2bf(xpv[0]); xpb.y = f2bf(xpv[1]); xpb.z = f2bf(xpv[2]); xpb.w = f2bf(xpv[3]);
        *(ushort4*)(xplain  + row * 256 + lane * 4) = xb;
        *(ushort4*)(xpplain + row * 256 + lane * 4) = xpb;
        ushort4 z; z.x = z.y = z.z = z.w = 0;
        if (l == 0) {
            *(ushort4*)(xplain  + ((size_t)b * PADL) * 256 + lane * 4) = z;
            *(ushort4*)(xpplain + ((size_t)b * PADL) * 256 + lane * 4) = z;
        }
        if (l == 255) {
            *(ushort4*)(xplain  + ((size_t)b * PADL + 257) * 256 + lane * 4) = z;
            *(ushort4*)(xpplain + ((size_t)b * PADL + 257) * 256 + lane * 4) = z;
        }
        // scatter x_pe into out rows [cum[l-1], cum[l])
        int start = l ? sc[l - 1] : 0;
        int end = sc[l];
        for (int tt = start; tt < end; ++tt)
            *(f32x4*)(out + ((size_t)(b * 2048 + tt)) * 256 + lane * 4) = xpev;
    } else if (bx < 2336) {
        // ---- weight transpose role ----
        float (*tile)[65] = (float(*)[65])smem;
        int id = bx - 2048;
        int tf = id & 3; int th = (id >> 2) & 3;
        int rest = id >> 4;
        int k = rest % 3; rest /= 3;
        int set = rest % 3; int tensor = rest / 3;
        const float* src = tensor ? w2 : w1;
        const float* s = src + (((size_t)set * 3 + k) * 256 + th * 64) * 256 + tf * 64;
        int fl = t & 63;
        int q = t >> 6;
#pragma unroll
        for (int i = 0; i < 16; ++i) {
            int hl = i * 4 + q;
            tile[hl][fl] = s[(size_t)hl * 256 + fl];
        }
        __syncthreads();
        size_t rowbase = (size_t)tensor * 768 + set * 256 + tf * 64;
        size_t colbase = (size_t)k * 256 + th * 64;
#pragma unroll
        for (int i = 0; i < 16; ++i) {
            int f2 = i * 4 + q;
            bt[(rowbase + f2) * KH + colbase + fl] = f2bf(tile[fl][f2]);
        }
    } else if (bx < 2368) {
        // ---- mel_len role ----
        int* sh = (int*)smem;
        int b = bx - 2336;
        sh[t] = dur[b * 256 + t];
        __syncthreads();
        for (int s = 128; s > 0; s >>= 1) {
            if (t < s) sh[t] += sh[t + s];
            __syncthreads();
        }
        if (t == 0) mel_len_out[b] = (float)sh[0];
    } else {
        // ---- zero-fill + mel_mask role: 32 mel rows per block ----
        int* sh = (int*)smem;
        int g = bx - 2368;
        int b = g >> 6;
        int t0 = (g & 63) * 32;
        sh[t] = dur[b * 256 + t];
        __syncthreads();
        for (int s = 128; s > 0; s >>= 1) {
            if (t < s) sh[t] += sh[t + s];
            __syncthreads();
        }
        int mel = sh[0];
        int w = t >> 6, lane = t & 63;
        f32x4 z4 = (f32x4){0.f, 0.f, 0.f, 0.f};
#pragma unroll
        for (int it = 0; it < 8; ++it) {
            int tt = t0 + it * 4 + w;
            if (tt >= mel)
                *(f32x4*)(out + ((size_t)(b * 2048 + tt)) * 256 + lane * 4) = z4;
        }
        if (t < 32) maskout[b * 2048 + t0 + t] = (t0 + t < mel) ? 0.f : 1.f;
    }
}

// ================= conv GEMM: 128x256 tile, 512 threads, BK=32; A staged ONCE; B dbuf =================
// A-LDS: 130 rows x 512B; phys byte = r*512 + (c ^ ((r&7)<<4)); pre-swizzled global src.
// B-LDS: 256 rows x 64B; phys byte = c*64 + (kb ^ ((c&3)<<4)).
__device__ __forceinline__ void stageA128(const unsigned short* __restrict__ A, int browPad,
                                          unsigned short* As, int tid) {
    for (int g = tid; g < 4160; g += 512) {
        int p = g * 16;
        int r = p >> 9;
        int c = (p & 511) ^ ((r & 7) << 4);
        __builtin_amdgcn_global_load_lds(
            (const __attribute__((address_space(1))) unsigned int*)((const char*)(A + (size_t)(browPad + r) * 256) + c),
            (__attribute__((address_space(3))) unsigned int*)((char*)As + p), 16, 0, 0);
    }
}

__device__ __forceinline__ void stageB128(const unsigned short* __restrict__ Bm, int kt,
                                          unsigned short* Bs, int tid) {
#pragma unroll
    for (int j = 0; j < 2; ++j) {
        int p = j * 8192 + tid * 16;
        int c = p >> 6;
        int kb = (p & 63) ^ ((c & 3) << 4);
        __builtin_amdgcn_global_load_lds(
            (const __attribute__((address_space(1))) unsigned int*)((const char*)(Bm + (size_t)c * KH + kt) + kb),
            (__attribute__((address_space(3))) unsigned int*)((char*)Bs + p), 16, 0, 0);
    }
}

__device__ __forceinline__ void compute128(const unsigned short* As, const unsigned short* Bs,
                                           int kt, int lane, int wr, int wc, f32x4 acc[4][4]) {
    const int rsel = lane & 15;
    const int lhi = lane >> 4;
    const int tap = kt >> 8;
    const int hcb = (kt & 255) * 2 + lhi * 16;
    bf16x8 af[4], bfr[4];
#pragma unroll
    for (int m = 0; m < 4; ++m) {
        int r = tap + wr * 64 + m * 16 + rsel;
        af[m] = *(const bf16x8*)((const char*)As + r * 512 + (hcb ^ ((r & 7) << 4)));
    }
#pragma unroll
    for (int n = 0; n < 4; ++n) {
        int c = wc * 64 + n * 16 + rsel;
        bfr[n] = *(const bf16x8*)((const char*)Bs + c * 64 + ((lhi * 16) ^ ((c & 3) << 4)));
    }
#pragma unroll
    for (int m = 0; m < 4; ++m)
#pragma unroll
        for (int n = 0; n < 4; ++n)
            acc[m][n] = __builtin_amdgcn_mfma_f32_16x16x32_bf16(af[m], bfr[n], acc[m][n], 0, 0, 0);
}

// ================= conv1 + bias + relu + LN -> padded bf16 h =================
__global__ __launch_bounds__(512) void k_conv_ln1(
        const unsigned short* __restrict__ xplain, const unsigned short* __restrict__ xpplain,
        const unsigned short* __restrict__ bt,
        const float* __restrict__ b1, const float* __restrict__ g1, const float* __restrict__ be1,
        unsigned short* __restrict__ h0, unsigned short* __restrict__ h1, unsigned short* __restrict__ h2) {
    __shared__ unsigned short As[33280];     // 130 rows x 512B, swizzled
    __shared__ unsigned short Bs[2][8192];   // 256 x 64B, swizzled, dbuf
    __shared__ float2 red[4][128];

    const int pred = blockIdx.y;
    const unsigned short* A  = (pred < 2) ? xplain : xpplain;
    const unsigned short* Bm = bt + (size_t)pred * 256 * KH;
    unsigned short* hout = (pred == 0) ? h0 : (pred == 1) ? h1 : h2;

    const int rowBase = blockIdx.x * 128;
    const int bb = rowBase >> 8;
    const int l0 = rowBase & 255;
    const int browPad = bb * PADL + l0;
    const int tid = threadIdx.x;
    const int lane = tid & 63;
    const int wv = tid >> 6;
    const int wr = wv >> 2, wc = wv & 3;
    const int rsel = lane & 15;
    const int lhi = lane >> 4;

    f32x4 acc[4][4];
#pragma unroll
    for (int m = 0; m < 4; ++m)
#pragma unroll
        for (int n = 0; n < 4; ++n) acc[m][n] = (f32x4){0.f, 0.f, 0.f, 0.f};

    stageA128(A, browPad, As, tid);
    stageB128(Bm, 0, Bs[0], tid);
    __syncthreads();
    int cur = 0;
    for (int kt = 32; kt < KH; kt += 32) {
        stageB128(Bm, kt, Bs[cur ^ 1], tid);
        compute128(As, Bs[cur], kt - 32, lane, wr, wc, acc);
        __syncthreads();
        cur ^= 1;
    }
    compute128(As, Bs[cur], KH - 32, lane, wr, wc, acc);

    float bcol[4], gcol[4], becol[4];
#pragma unroll
    for (int n = 0; n < 4; ++n) {
        int c = wc * 64 + n * 16 + rsel;
        bcol[n] = b1[pred * 256 + c];
        gcol[n] = g1[pred * 256 + c];
        becol[n] = be1[pred * 256 + c];
    }

#pragma unroll
    for (int m = 0; m < 4; ++m)
#pragma unroll
        for (int r = 0; r < 4; ++r) {
            float s = 0.f, s2 = 0.f;
#pragma unroll
            for (int n = 0; n < 4; ++n) {
                float v = fmaxf(acc[m][n][r] + bcol[n], 0.f);
                s += v; s2 += v * v;
            }
#pragma unroll
            for (int o = 1; o < 16; o <<= 1) { s += __shfl_xor(s, o); s2 += __shfl_xor(s2, o); }
            if (rsel == 0) red[wc][wr * 64 + m * 16 + lhi * 4 + r] = make_float2(s, s2);
        }
    __syncthreads();
    if (tid < 128) {
        float2 a0 = red[0][tid], a1 = red[1][tid], a2 = red[2][tid], a3 = red[3][tid];
        red[0][tid] = make_float2(a0.x + a1.x + a2.x + a3.x, a0.y + a1.y + a2.y + a3.y);
    }
    __syncthreads();

#pragma unroll
    for (int m = 0; m < 4; ++m)
#pragma unroll
        for (int r = 0; r < 4; ++r) {
            int rl = wr * 64 + m * 16 + lhi * 4 + r;
            float2 t = red[0][rl];
            float mean = t.x * (1.f / 256.f);
            float var = t.y * (1.f / 256.f) - mean * mean;
            float inv = rsqrtf(var + EPS_);
            int l = l0 + rl;
            size_t row = (size_t)bb * PADL + 1 + l;
#pragma unroll
            for (int n = 0; n < 4; ++n) {
                float v = fmaxf(acc[m][n][r] + bcol[n], 0.f);
                float h = (v - mean) * inv * gcol[n] + becol[n];
                int c = wc * 64 + n * 16 + rsel;
                hout[row * 256 + c] = f2bf(h);
                if (l == 0)   hout[((size_t)bb * PADL) * 256 + c] = 0;
                if (l == 255) hout[((size_t)bb * PADL + 257) * 256 + c] = 0;
            }
        }
}

// ================= conv2 + bias + relu + LN + dot(wl) + mask -> predictions =================
__global__ __launch_bounds__(512) void k_conv_ln2(
        const unsigned short* __restrict__ h0, const unsigned short* __restrict__ h1,
        const unsigned short* __restrict__ h2, const unsigned short* __restrict__ bt,
        const float* __restrict__ b2, const float* __restrict__ g2, const float* __restrict__ be2,
        const float* __restrict__ wl, const float* __restrict__ bl,
        const char* __restrict__ mask, float* __restrict__ outp) {
    __shared__ unsigned short As[33280];
    __shared__ unsigned short Bs[2][8192];
    __shared__ float2 red[4][128];
    __shared__ float  red2[4][128];

    const int pred = blockIdx.y;
    const unsigned short* A  = (pred == 0) ? h0 : (pred == 1) ? h1 : h2;
    const unsigned short* Bm = bt + (size_t)(768 + pred * 256) * KH;

    const int rowBase = blockIdx.x * 128;
    const int bb = rowBase >> 8;
    const int l0 = rowBase & 255;
    const int browPad = bb * PADL + l0;
    const int tid = threadIdx.x;
    const int lane = tid & 63;
    const int wv = tid >> 6;
    const int wr = wv >> 2, wc = wv & 3;
    const int rsel = lane & 15;
    const int lhi = lane >> 4;

    f32x4 acc[4][4];
#pragma unroll
    for (int m = 0; m < 4; ++m)
#pragma unroll
        for (int n = 0; n < 4; ++n) acc[m][n] = (f32x4){0.f, 0.f, 0.f, 0.f};

    stageA128(A, browPad, As, tid);
    stageB128(Bm, 0, Bs[0], tid);
    __syncthreads();
    int cur = 0;
    for (int kt = 32; kt < KH; kt += 32) {
        stageB128(Bm, kt, Bs[cur ^ 1], tid);
        compute128(As, Bs[cur], kt - 32, lane, wr, wc, acc);
        __syncthreads();
        cur ^= 1;
    }
    compute128(As, Bs[cur], KH - 32, lane, wr, wc, acc);

    float bcol[4], gcol[4], becol[4], wcol[4];
#pragma unroll
    for (int n = 0; n < 4; ++n) {
        int c = wc * 64 + n * 16 + rsel;
        bcol[n] = b2[pred * 256 + c];
        gcol[n] = g2[pred * 256 + c];
        becol[n] = be2[pred * 256 + c];
        wcol[n] = wl[pred * 256 + c];
    }

#pragma unroll
    for (int m = 0; m < 4; ++m)
#pragma unroll
        for (int r = 0; r < 4; ++r) {
            float s = 0.f, s2 = 0.f;
#pragma unroll
            for (int n = 0; n < 4; ++n) {
                float v = fmaxf(acc[m][n][r] + bcol[n], 0.f);
                s += v; s2 += v * v;
            }
#pragma unroll
            for (int o = 1; o < 16; o <<= 1) { s += __shfl_xor(s, o); s2 += __shfl_xor(s2, o); }
            if (rsel == 0) red[wc][wr * 64 + m * 16 + lhi * 4 + r] = make_float2(s, s2);
        }
    __syncthreads();
    if (tid < 128) {
        float2 a0 = red[0][tid], a1 = red[1][tid], a2 = red[2][tid], a3 = red[3][tid];
        red[0][tid] = make_float2(a0.x + a1.x + a2.x + a3.x, a0.y + a1.y + a2.y + a3.y);
    }
    __syncthreads();

#pragma unroll
    for (int m = 0; m < 4; ++m)
#pragma unroll
        for (int r = 0; r < 4; ++r) {
            int rl = wr * 64 + m * 16 + lhi * 4 + r;
            float2 t = red[0][rl];
            float mean = t.x * (1.f / 256.f);
            float var = t.y * (1.f / 256.f) - mean * mean;
            float inv = rsqrtf(var + EPS_);
            float d = 0.f;
#pragma unroll
            for (int n = 0; n < 4; ++n) {
                float v = fmaxf(acc[m][n][r] + bcol[n], 0.f);
                float h = (v - mean) * inv * gcol[n] + becol[n];
                d += h * wcol[n];
            }
#pragma unroll
            for (int o = 1; o < 16; o <<= 1) d += __shfl_xor(d, o);
            if (rsel == 0) red2[wc][rl] = d;
        }
    __syncthreads();
    if (tid < 128) {
        int p = rowBase + tid;
        float o = red2[0][tid] + red2[1][tid] + red2[2][tid] + red2[3][tid] + bl[pred];
        if (mask[p]) o = 0.f;
        outp[(size_t)pred * P_TOT + p] = o;
    }
}

extern "C" void kernel_launch(void* const* d_in, const int* in_sizes, int n_in,
                              void* d_out, int out_size, void* d_ws, size_t ws_size,
                              hipStream_t stream) {
    const float* x     = (const float*)d_in[0];
    const float* pt    = (const float*)d_in[1];
    const float* et    = (const float*)d_in[2];
    const float* w1    = (const float*)d_in[3];
    const float* b1    = (const float*)d_in[4];
    const float* g1    = (const float*)d_in[5];
    const float* be1   = (const float*)d_in[6];
    const float* w2    = (const float*)d_in[7];
    const float* b2    = (const float*)d_in[8];
    const float* g2    = (const float*)d_in[9];
    const float* be2   = (const float*)d_in[10];
    const float* wl    = (const float*)d_in[11];
    const float* bl    = (const float*)d_in[12];
    const float* pbins = (const float*)d_in[13];
    const float* ebins = (const float*)d_in[14];
    const float* pemb  = (const float*)d_in[15];
    const float* eemb  = (const float*)d_in[16];
    const char*  mask  = (const char*)d_in[17];
    const int*   dur   = (const int*)d_in[18];

    char* ws = (char*)d_ws;
    unsigned short* xplain  = (unsigned short*)(ws + 0);
    unsigned short* xpplain = (unsigned short*)(ws + 8388608);
    unsigned short* h0      = (unsigned short*)(ws + 16777216);
    unsigned short* h1      = (unsigned short*)(ws + 25165824);
    unsigned short* h2      = (unsigned short*)(ws + 33554432);
    unsigned short* btall   = (unsigned short*)(ws + 52428800);

    float* out        = (float*)d_out;
    float* out_pred   = out + 16777216;           // log_dur | pitch | energy (8192 each)
    float* out_mellen = out + 16801792;
    float* out_mask   = out + 16801824;

    hipLaunchKernelGGL(k_pre, dim3(4416), dim3(256), 0, stream,
                       x, pt, et, pbins, ebins, pemb, eemb, w1, w2, dur,
                       xplain, xpplain, btall, out, out_mask, out_mellen);

    hipLaunchKernelGGL(k_conv_ln1, dim3(64, 3), dim3(512), 0, stream,
                       xplain, xpplain, btall, b1, g1, be1, h0, h1, h2);

    hipLaunchKernelGGL(k_conv_ln2, dim3(64, 3), dim3(512), 0, stream,
                       h0, h1, h2, btall, b2, g2, be2, wl, bl, mask, out_pred);
}

// Round 13
// 63.870 us; speedup vs baseline: 1.3373x; 1.1566x over previous
//
#include <hip/hip_runtime.h>
#include <hip/hip_bf16.h>
#include <cstdint>

typedef float f32x4 __attribute__((ext_vector_type(4)));
typedef short bf16x8 __attribute__((ext_vector_type(8)));

#define P_TOT 8192      // B*L
#define KH 768          // K*H (GEMM K-dim)
#define PADL 258        // padded sequence length (zero row before & after)
#define EPS_ 1e-5f

__device__ __forceinline__ unsigned short f2bf(float f) {
    unsigned int x = __float_as_uint(f);
    unsigned int r = (x + 0x7fffu + ((x >> 16) & 1u)) >> 16;
    return (unsigned short)r;
}

// ==== fused pre-kernel: embed+scatter (2048) | wtrans (288) | mel_len (32) | zero-fill (2048) ====
__global__ __launch_bounds__(256) void k_pre(
        const float* __restrict__ x, const float* __restrict__ pt, const float* __restrict__ et,
        const float* __restrict__ pbins, const float* __restrict__ ebins,
        const float* __restrict__ pemb, const float* __restrict__ eemb,
        const float* __restrict__ w1, const float* __restrict__ w2,
        const int* __restrict__ dur,
        unsigned short* __restrict__ xplain, unsigned short* __restrict__ xpplain,
        unsigned short* __restrict__ bt,
        float* __restrict__ out, float* __restrict__ maskout, float* __restrict__ mel_len_out) {
    __shared__ char smem[16640];
    const int bx = blockIdx.x;
    const int t = threadIdx.x;

    if (bx < 2048) {
        // ---- embed + length-regulate scatter role: 4 rows of one batch per block ----
        float* pb = (float*)smem;              // 256 f
        float* eb = pb + 256;                  // 256 f
        int*   sc = (int*)(eb + 256);          // 256 i (inclusive cumsum)
        const int b = bx >> 6;                 // batch (4 rows/block, 64 blocks/batch)
        if (t < 255) { pb[t] = pbins[t]; eb[t] = ebins[t]; }
        sc[t] = dur[b * 256 + t];
        for (int s = 1; s < 256; s <<= 1) {
            __syncthreads();
            int add = (t >= s) ? sc[t - s] : 0;
            __syncthreads();
            sc[t] += add;
        }
        __syncthreads();

        int w = t >> 6, lane = t & 63;
        int p = bx * 4 + w; int l = p & 255;
        float ptv = pt[p], etv = et[p];
        int lo = 0, hi = 255;
        while (lo < hi) { int mid = (lo + hi) >> 1; if (pb[mid] < ptv) lo = mid + 1; else hi = mid; }
        int pidx = lo;
        lo = 0; hi = 255;
        while (lo < hi) { int mid = (lo + hi) >> 1; if (eb[mid] < etv) lo = mid + 1; else hi = mid; }
        int eidx = lo;
        f32x4 xv = *(const f32x4*)(x    + (size_t)p * 256 + lane * 4);
        f32x4 pe = *(const f32x4*)(pemb + (size_t)pidx * 256 + lane * 4);
        f32x4 ee = *(const f32x4*)(eemb + (size_t)eidx * 256 + lane * 4);
        f32x4 xpv = xv + pe;
        f32x4 xpev = xpv + ee;
        size_t row = (size_t)b * PADL + 1 + l;
        ushort4 xb, xpb;
        xb.x = f2bf(xv[0]);  xb.y = f2bf(xv[1]);  xb.z = f2bf(xv[2]);  xb.w = f2bf(xv[3]);
        xpb.x = f2bf(xpv[0]); xpb.y = f2bf(xpv[1]); xpb.z = f2bf(xpv[2]); xpb.w = f2bf(xpv[3]);
        *(ushort4*)(xplain  + row * 256 + lane * 4) = xb;
        *(ushort4*)(xpplain + row * 256 + lane * 4) = xpb;
        ushort4 z; z.x = z.y = z.z = z.w = 0;
        if (l == 0) {
            *(ushort4*)(xplain  + ((size_t)b * PADL) * 256 + lane * 4) = z;
            *(ushort4*)(xpplain + ((size_t)b * PADL) * 256 + lane * 4) = z;
        }
        if (l == 255) {
            *(ushort4*)(xplain  + ((size_t)b * PADL + 257) * 256 + lane * 4) = z;
            *(ushort4*)(xpplain + ((size_t)b * PADL + 257) * 256 + lane * 4) = z;
        }
        // scatter x_pe into out rows [cum[l-1], cum[l])
        int start = l ? sc[l - 1] : 0;
        int end = sc[l];
        for (int tt = start; tt < end; ++tt)
            *(f32x4*)(out + ((size_t)(b * 2048 + tt)) * 256 + lane * 4) = xpev;
    } else if (bx < 2336) {
        // ---- weight transpose role ----
        float (*tile)[65] = (float(*)[65])smem;
        int id = bx - 2048;
        int tf = id & 3; int th = (id >> 2) & 3;
        int rest = id >> 4;
        int k = rest % 3; rest /= 3;
        int set = rest % 3; int tensor = rest / 3;
        const float* src = tensor ? w2 : w1;
        const float* s = src + (((size_t)set * 3 + k) * 256 + th * 64) * 256 + tf * 64;
        int fl = t & 63;
        int q = t >> 6;
#pragma unroll
        for (int i = 0; i < 16; ++i) {
            int hl = i * 4 + q;
            tile[hl][fl] = s[(size_t)hl * 256 + fl];
        }
        __syncthreads();
        size_t rowbase = (size_t)tensor * 768 + set * 256 + tf * 64;
        size_t colbase = (size_t)k * 256 + th * 64;
#pragma unroll
        for (int i = 0; i < 16; ++i) {
            int f2 = i * 4 + q;
            bt[(rowbase + f2) * KH + colbase + fl] = f2bf(tile[fl][f2]);
        }
    } else if (bx < 2368) {
        // ---- mel_len role ----
        int* sh = (int*)smem;
        int b = bx - 2336;
        sh[t] = dur[b * 256 + t];
        __syncthreads();
        for (int s = 128; s > 0; s >>= 1) {
            if (t < s) sh[t] += sh[t + s];
            __syncthreads();
        }
        if (t == 0) mel_len_out[b] = (float)sh[0];
    } else {
        // ---- zero-fill + mel_mask role: 32 mel rows per block ----
        int* sh = (int*)smem;
        int g = bx - 2368;
        int b = g >> 6;
        int t0 = (g & 63) * 32;
        sh[t] = dur[b * 256 + t];
        __syncthreads();
        for (int s = 128; s > 0; s >>= 1) {
            if (t < s) sh[t] += sh[t + s];
            __syncthreads();
        }
        int mel = sh[0];
        int w = t >> 6, lane = t & 63;
        f32x4 z4 = (f32x4){0.f, 0.f, 0.f, 0.f};
#pragma unroll
        for (int it = 0; it < 8; ++it) {
            int tt = t0 + it * 4 + w;
            if (tt >= mel)
                *(f32x4*)(out + ((size_t)(b * 2048 + tt)) * 256 + lane * 4) = z4;
        }
        if (t < 32) maskout[b * 2048 + t0 + t] = (t0 + t < mel) ? 0.f : 1.f;
    }
}

// ================= conv GEMM: 128x256 tile, 512 threads, BK=32 =================
// A staged ONCE (swizzled); B: 3-buffer counted-vmcnt pipeline (one s_barrier/step).
// A-LDS: 130 rows x 512B; phys byte = r*512 + (c ^ ((r&7)<<4)); pre-swizzled global src.
// B-LDS: 256 rows x 64B; phys byte = c*64 + (kb ^ ((c&3)<<4)). 2 loads/thread/step (uniform).
__device__ __forceinline__ void stageA128(const unsigned short* __restrict__ A, int browPad,
                                          unsigned short* As, int tid) {
    for (int g = tid; g < 4160; g += 512) {
        int p = g * 16;
        int r = p >> 9;
        int c = (p & 511) ^ ((r & 7) << 4);
        __builtin_amdgcn_global_load_lds(
            (const __attribute__((address_space(1))) unsigned int*)((const char*)(A + (size_t)(browPad + r) * 256) + c),
            (__attribute__((address_space(3))) unsigned int*)((char*)As + p), 16, 0, 0);
    }
}

__device__ __forceinline__ void stageB128(const unsigned short* __restrict__ Bm, int kt,
                                          unsigned short* Bs, int tid) {
#pragma unroll
    for (int j = 0; j < 2; ++j) {
        int p = j * 8192 + tid * 16;
        int c = p >> 6;
        int kb = (p & 63) ^ ((c & 3) << 4);
        __builtin_amdgcn_global_load_lds(
            (const __attribute__((address_space(1))) unsigned int*)((const char*)(Bm + (size_t)c * KH + kt) + kb),
            (__attribute__((address_space(3))) unsigned int*)((char*)Bs + p), 16, 0, 0);
    }
}

__device__ __forceinline__ void compute128(const unsigned short* As, const unsigned short* Bs,
                                           int kt, int lane, int wr, int wc, f32x4 acc[4][4]) {
    const int rsel = lane & 15;
    const int lhi = lane >> 4;
    const int tap = kt >> 8;
    const int hcb = (kt & 255) * 2 + lhi * 16;
    bf16x8 af[4], bfr[4];
#pragma unroll
    for (int m = 0; m < 4; ++m) {
        int r = tap + wr * 64 + m * 16 + rsel;
        af[m] = *(const bf16x8*)((const char*)As + r * 512 + (hcb ^ ((r & 7) << 4)));
    }
#pragma unroll
    for (int n = 0; n < 4; ++n) {
        int c = wc * 64 + n * 16 + rsel;
        bfr[n] = *(const bf16x8*)((const char*)Bs + c * 64 + ((lhi * 16) ^ ((c & 3) << 4)));
    }
#pragma unroll
    for (int m = 0; m < 4; ++m)
#pragma unroll
        for (int n = 0; n < 4; ++n)
            acc[m][n] = __builtin_amdgcn_mfma_f32_16x16x32_bf16(af[m], bfr[n], acc[m][n], 0, 0, 0);
}

// K sweep: 3 B-buffers, depth-2 prefetch, counted vmcnt (never 0 in steady state),
// one raw barrier per step. Prologue: B0, A, B1 issued; vmcnt(2) leaves B1 in flight.
__device__ __forceinline__ void conv_kloop(const unsigned short* __restrict__ A,
                                           const unsigned short* __restrict__ Bm,
                                           int browPad, int lane, int wr, int wc, int tid,
                                           unsigned short* As, unsigned short (*Bs)[8192],
                                           f32x4 acc[4][4]) {
    stageB128(Bm, 0, Bs[0], tid);
    stageA128(A, browPad, As, tid);
    stageB128(Bm, 32, Bs[1], tid);
#pragma unroll
    for (int t = 0; t < 24; ++t) {
        // stage t must be landed; stage t+1 (newest 2 loads) may stay in flight
        if (t <= 21) asm volatile("s_waitcnt vmcnt(2)" ::: "memory");
        else         asm volatile("s_waitcnt vmcnt(0)" ::: "memory");
        __builtin_amdgcn_s_barrier();
        __builtin_amdgcn_sched_barrier(0);
        if (t + 2 < 24)
            stageB128(Bm, (t + 2) * 32, Bs[(t + 2) % 3], tid);
        compute128(As, Bs[t % 3], t * 32, lane, wr, wc, acc);
    }
    __syncthreads();
}

// ================= conv1 + bias + relu + LN -> padded bf16 h =================
__global__ __launch_bounds__(512) void k_conv_ln1(
        const unsigned short* __restrict__ xplain, const unsigned short* __restrict__ xpplain,
        const unsigned short* __restrict__ bt,
        const float* __restrict__ b1, const float* __restrict__ g1, const float* __restrict__ be1,
        unsigned short* __restrict__ h0, unsigned short* __restrict__ h1, unsigned short* __restrict__ h2) {
    __shared__ unsigned short As[33280];     // 130 rows x 512B, swizzled
    __shared__ unsigned short Bs[3][8192];   // 256 x 64B, swizzled, 3-buf
    __shared__ float2 red[4][128];

    const int pred = blockIdx.y;
    const unsigned short* A  = (pred < 2) ? xplain : xpplain;
    const unsigned short* Bm = bt + (size_t)pred * 256 * KH;
    unsigned short* hout = (pred == 0) ? h0 : (pred == 1) ? h1 : h2;

    const int rowBase = blockIdx.x * 128;
    const int bb = rowBase >> 8;
    const int l0 = rowBase & 255;
    const int browPad = bb * PADL + l0;
    const int tid = threadIdx.x;
    const int lane = tid & 63;
    const int wv = tid >> 6;
    const int wr = wv >> 2, wc = wv & 3;
    const int rsel = lane & 15;
    const int lhi = lane >> 4;

    f32x4 acc[4][4];
#pragma unroll
    for (int m = 0; m < 4; ++m)
#pragma unroll
        for (int n = 0; n < 4; ++n) acc[m][n] = (f32x4){0.f, 0.f, 0.f, 0.f};

    conv_kloop(A, Bm, browPad, lane, wr, wc, tid, As, Bs, acc);

    float bcol[4], gcol[4], becol[4];
#pragma unroll
    for (int n = 0; n < 4; ++n) {
        int c = wc * 64 + n * 16 + rsel;
        bcol[n] = b1[pred * 256 + c];
        gcol[n] = g1[pred * 256 + c];
        becol[n] = be1[pred * 256 + c];
    }

#pragma unroll
    for (int m = 0; m < 4; ++m)
#pragma unroll
        for (int r = 0; r < 4; ++r) {
            float s = 0.f, s2 = 0.f;
#pragma unroll
            for (int n = 0; n < 4; ++n) {
                float v = fmaxf(acc[m][n][r] + bcol[n], 0.f);
                s += v; s2 += v * v;
            }
#pragma unroll
            for (int o = 1; o < 16; o <<= 1) { s += __shfl_xor(s, o); s2 += __shfl_xor(s2, o); }
            if (rsel == 0) red[wc][wr * 64 + m * 16 + lhi * 4 + r] = make_float2(s, s2);
        }
    __syncthreads();
    if (tid < 128) {
        float2 a0 = red[0][tid], a1 = red[1][tid], a2 = red[2][tid], a3 = red[3][tid];
        red[0][tid] = make_float2(a0.x + a1.x + a2.x + a3.x, a0.y + a1.y + a2.y + a3.y);
    }
    __syncthreads();

#pragma unroll
    for (int m = 0; m < 4; ++m)
#pragma unroll
        for (int r = 0; r < 4; ++r) {
            int rl = wr * 64 + m * 16 + lhi * 4 + r;
            float2 t = red[0][rl];
            float mean = t.x * (1.f / 256.f);
            float var = t.y * (1.f / 256.f) - mean * mean;
            float inv = rsqrtf(var + EPS_);
            int l = l0 + rl;
            size_t row = (size_t)bb * PADL + 1 + l;
#pragma unroll
            for (int n = 0; n < 4; ++n) {
                float v = fmaxf(acc[m][n][r] + bcol[n], 0.f);
                float h = (v - mean) * inv * gcol[n] + becol[n];
                int c = wc * 64 + n * 16 + rsel;
                hout[row * 256 + c] = f2bf(h);
                if (l == 0)   hout[((size_t)bb * PADL) * 256 + c] = 0;
                if (l == 255) hout[((size_t)bb * PADL + 257) * 256 + c] = 0;
            }
        }
}

// ================= conv2 + bias + relu + LN + dot(wl) + mask -> predictions =================
__global__ __launch_bounds__(512) void k_conv_ln2(
        const unsigned short* __restrict__ h0, const unsigned short* __restrict__ h1,
        const unsigned short* __restrict__ h2, const unsigned short* __restrict__ bt,
        const float* __restrict__ b2, const float* __restrict__ g2, const float* __restrict__ be2,
        const float* __restrict__ wl, const float* __restrict__ bl,
        const char* __restrict__ mask, float* __restrict__ outp) {
    __shared__ unsigned short As[33280];
    __shared__ unsigned short Bs[3][8192];
    __shared__ float2 red[4][128];
    __shared__ float  red2[4][128];

    const int pred = blockIdx.y;
    const unsigned short* A  = (pred == 0) ? h0 : (pred == 1) ? h1 : h2;
    const unsigned short* Bm = bt + (size_t)(768 + pred * 256) * KH;

    const int rowBase = blockIdx.x * 128;
    const int bb = rowBase >> 8;
    const int l0 = rowBase & 255;
    const int browPad = bb * PADL + l0;
    const int tid = threadIdx.x;
    const int lane = tid & 63;
    const int wv = tid >> 6;
    const int wr = wv >> 2, wc = wv & 3;
    const int rsel = lane & 15;
    const int lhi = lane >> 4;

    f32x4 acc[4][4];
#pragma unroll
    for (int m = 0; m < 4; ++m)
#pragma unroll
        for (int n = 0; n < 4; ++n) acc[m][n] = (f32x4){0.f, 0.f, 0.f, 0.f};

    conv_kloop(A, Bm, browPad, lane, wr, wc, tid, As, Bs, acc);

    float bcol[4], gcol[4], becol[4], wcol[4];
#pragma unroll
    for (int n = 0; n < 4; ++n) {
        int c = wc * 64 + n * 16 + rsel;
        bcol[n] = b2[pred * 256 + c];
        gcol[n] = g2[pred * 256 + c];
        becol[n] = be2[pred * 256 + c];
        wcol[n] = wl[pred * 256 + c];
    }

#pragma unroll
    for (int m = 0; m < 4; ++m)
#pragma unroll
        for (int r = 0; r < 4; ++r) {
            float s = 0.f, s2 = 0.f;
#pragma unroll
            for (int n = 0; n < 4; ++n) {
                float v = fmaxf(acc[m][n][r] + bcol[n], 0.f);
                s += v; s2 += v * v;
            }
#pragma unroll
            for (int o = 1; o < 16; o <<= 1) { s += __shfl_xor(s, o); s2 += __shfl_xor(s2, o); }
            if (rsel == 0) red[wc][wr * 64 + m * 16 + lhi * 4 + r] = make_float2(s, s2);
        }
    __syncthreads();
    if (tid < 128) {
        float2 a0 = red[0][tid], a1 = red[1][tid], a2 = red[2][tid], a3 = red[3][tid];
        red[0][tid] = make_float2(a0.x + a1.x + a2.x + a3.x, a0.y + a1.y + a2.y + a3.y);
    }
    __syncthreads();

#pragma unroll
    for (int m = 0; m < 4; ++m)
#pragma unroll
        for (int r = 0; r < 4; ++r) {
            int rl = wr * 64 + m * 16 + lhi * 4 + r;
            float2 t = red[0][rl];
            float mean = t.x * (1.f / 256.f);
            float var = t.y * (1.f / 256.f) - mean * mean;
            float inv = rsqrtf(var + EPS_);
            float d = 0.f;
#pragma unroll
            for (int n = 0; n < 4; ++n) {
                float v = fmaxf(acc[m][n][r] + bcol[n], 0.f);
                float h = (v - mean) * inv * gcol[n] + becol[n];
                d += h * wcol[n];
            }
#pragma unroll
            for (int o = 1; o < 16; o <<= 1) d += __shfl_xor(d, o);
            if (rsel == 0) red2[wc][rl] = d;
        }
    __syncthreads();
    if (tid < 128) {
        int p = rowBase + tid;
        float o = red2[0][tid] + red2[1][tid] + red2[2][tid] + red2[3][tid] + bl[pred];
        if (mask[p]) o = 0.f;
        outp[(size_t)pred * P_TOT + p] = o;
    }
}

extern "C" void kernel_launch(void* const* d_in, const int* in_sizes, int n_in,
                              void* d_out, int out_size, void* d_ws, size_t ws_size,
                              hipStream_t stream) {
    const float* x     = (const float*)d_in[0];
    const float* pt    = (const float*)d_in[1];
    const float* et    = (const float*)d_in[2];
    const float* w1    = (const float*)d_in[3];
    const float* b1    = (const float*)d_in[4];
    const float* g1    = (const float*)d_in[5];
    const float* be1   = (const float*)d_in[6];
    const float* w2    = (const float*)d_in[7];
    const float* b2    = (const float*)d_in[8];
    const float* g2    = (const float*)d_in[9];
    const float* be2   = (const float*)d_in[10];
    const float* wl    = (const float*)d_in[11];
    const float* bl    = (const float*)d_in[12];
    const float* pbins = (const float*)d_in[13];
    const float* ebins = (const float*)d_in[14];
    const float* pemb  = (const float*)d_in[15];
    const float* eemb  = (const float*)d_in[16];
    const char*  mask  = (const char*)d_in[17];
    const int*   dur   = (const int*)d_in[18];

    char* ws = (char*)d_ws;
    unsigned short* xplain  = (unsigned short*)(ws + 0);
    unsigned short* xpplain = (unsigned short*)(ws + 8388608);
    unsigned short* h0      = (unsigned short*)(ws + 16777216);
    unsigned short* h1      = (unsigned short*)(ws + 25165824);
    unsigned short* h2      = (unsigned short*)(ws + 33554432);
    unsigned short* btall   = (unsigned short*)(ws + 52428800);

    float* out        = (float*)d_out;
    float* out_pred   = out + 16777216;           // log_dur | pitch | energy (8192 each)
    float* out_mellen = out + 16801792;
    float* out_mask   = out + 16801824;

    hipLaunchKernelGGL(k_pre, dim3(4416), dim3(256), 0, stream,
                       x, pt, et, pbins, ebins, pemb, eemb, w1, w2, dur,
                       xplain, xpplain, btall, out, out_mask, out_mellen);

    hipLaunchKernelGGL(k_conv_ln1, dim3(64, 3), dim3(512), 0, stream,
                       xplain, xpplain, btall, b1, g1, be1, h0, h1, h2);

    hipLaunchKernelGGL(k_conv_ln2, dim3(64, 3), dim3(512), 0, stream,
                       h0, h1, h2, btall, b2, g2, be2, wl, bl, mask, out_pred);
}

// Round 14
// 63.412 us; speedup vs baseline: 1.3470x; 1.0072x over previous
//
#include <hip/hip_runtime.h>
#include <hip/hip_bf16.h>
#include <cstdint>

typedef float f32x4 __attribute__((ext_vector_type(4)));
typedef short bf16x8 __attribute__((ext_vector_type(8)));

#define P_TOT 8192      // B*L
#define KH 768          // K*H (GEMM K-dim)
#define PADL 258        // padded sequence length (zero row before & after)
#define EPS_ 1e-5f

__device__ __forceinline__ unsigned short f2bf(float f) {
    unsigned int x = __float_as_uint(f);
    unsigned int r = (x + 0x7fffu + ((x >> 16) & 1u)) >> 16;
    return (unsigned short)r;
}

// ==== fused pre-kernel: embed+scatter (2048) | wtrans (288) | mel_len (32) | zero-fill (2048) ====
__global__ __launch_bounds__(256) void k_pre(
        const float* __restrict__ x, const float* __restrict__ pt, const float* __restrict__ et,
        const float* __restrict__ pbins, const float* __restrict__ ebins,
        const float* __restrict__ pemb, const float* __restrict__ eemb,
        const float* __restrict__ w1, const float* __restrict__ w2,
        const int* __restrict__ dur,
        unsigned short* __restrict__ xplain, unsigned short* __restrict__ xpplain,
        unsigned short* __restrict__ bt,
        float* __restrict__ out, float* __restrict__ maskout, float* __restrict__ mel_len_out) {
    __shared__ char smem[16640];
    const int bx = blockIdx.x;
    const int t = threadIdx.x;

    if (bx < 2048) {
        // ---- embed + length-regulate scatter role: 4 rows of one batch per block ----
        float* pb = (float*)smem;              // 256 f
        float* eb = pb + 256;                  // 256 f
        int*   sc = (int*)(eb + 256);          // 256 i (inclusive cumsum)
        const int b = bx >> 6;                 // batch (4 rows/block, 64 blocks/batch)
        if (t < 255) { pb[t] = pbins[t]; eb[t] = ebins[t]; }
        sc[t] = dur[b * 256 + t];
        for (int s = 1; s < 256; s <<= 1) {
            __syncthreads();
            int add = (t >= s) ? sc[t - s] : 0;
            __syncthreads();
            sc[t] += add;
        }
        __syncthreads();

        int w = t >> 6, lane = t & 63;
        int p = bx * 4 + w; int l = p & 255;
        float ptv = pt[p], etv = et[p];
        int lo = 0, hi = 255;
        while (lo < hi) { int mid = (lo + hi) >> 1; if (pb[mid] < ptv) lo = mid + 1; else hi = mid; }
        int pidx = lo;
        lo = 0; hi = 255;
        while (lo < hi) { int mid = (lo + hi) >> 1; if (eb[mid] < etv) lo = mid + 1; else hi = mid; }
        int eidx = lo;
        f32x4 xv = *(const f32x4*)(x    + (size_t)p * 256 + lane * 4);
        f32x4 pe = *(const f32x4*)(pemb + (size_t)pidx * 256 + lane * 4);
        f32x4 ee = *(const f32x4*)(eemb + (size_t)eidx * 256 + lane * 4);
        f32x4 xpv = xv + pe;
        f32x4 xpev = xpv + ee;
        size_t row = (size_t)b * PADL + 1 + l;
        ushort4 xb, xpb;
        xb.x = f2bf(xv[0]);  xb.y = f2bf(xv[1]);  xb.z = f2bf(xv[2]);  xb.w = f2bf(xv[3]);
        xpb.x = f2bf(xpv[0]); xpb.y = f2bf(xpv[1]); xpb.z = f2bf(xpv[2]); xpb.w = f2bf(xpv[3]);
        *(ushort4*)(xplain  + row * 256 + lane * 4) = xb;
        *(ushort4*)(xpplain + row * 256 + lane * 4) = xpb;
        ushort4 z; z.x = z.y = z.z = z.w = 0;
        if (l == 0) {
            *(ushort4*)(xplain  + ((size_t)b * PADL) * 256 + lane * 4) = z;
            *(ushort4*)(xpplain + ((size_t)b * PADL) * 256 + lane * 4) = z;
        }
        if (l == 255) {
            *(ushort4*)(xplain  + ((size_t)b * PADL + 257) * 256 + lane * 4) = z;
            *(ushort4*)(xpplain + ((size_t)b * PADL + 257) * 256 + lane * 4) = z;
        }
        // scatter x_pe into out rows [cum[l-1], cum[l])  (non-temporal: write-once stream)
        int start = l ? sc[l - 1] : 0;
        int end = sc[l];
        for (int tt = start; tt < end; ++tt)
            __builtin_nontemporal_store(xpev,
                (f32x4*)(out + ((size_t)(b * 2048 + tt)) * 256 + lane * 4));
    } else if (bx < 2336) {
        // ---- weight transpose role ----
        float (*tile)[65] = (float(*)[65])smem;
        int id = bx - 2048;
        int tf = id & 3; int th = (id >> 2) & 3;
        int rest = id >> 4;
        int k = rest % 3; rest /= 3;
        int set = rest % 3; int tensor = rest / 3;
        const float* src = tensor ? w2 : w1;
        const float* s = src + (((size_t)set * 3 + k) * 256 + th * 64) * 256 + tf * 64;
        int fl = t & 63;
        int q = t >> 6;
#pragma unroll
        for (int i = 0; i < 16; ++i) {
            int hl = i * 4 + q;
            tile[hl][fl] = s[(size_t)hl * 256 + fl];
        }
        __syncthreads();
        size_t rowbase = (size_t)tensor * 768 + set * 256 + tf * 64;
        size_t colbase = (size_t)k * 256 + th * 64;
#pragma unroll
        for (int i = 0; i < 16; ++i) {
            int f2 = i * 4 + q;
            bt[(rowbase + f2) * KH + colbase + fl] = f2bf(tile[fl][f2]);
        }
    } else if (bx < 2368) {
        // ---- mel_len role ----
        int* sh = (int*)smem;
        int b = bx - 2336;
        sh[t] = dur[b * 256 + t];
        __syncthreads();
        for (int s = 128; s > 0; s >>= 1) {
            if (t < s) sh[t] += sh[t + s];
            __syncthreads();
        }
        if (t == 0) mel_len_out[b] = (float)sh[0];
    } else {
        // ---- zero-fill + mel_mask role: 32 mel rows per block ----
        int* sh = (int*)smem;
        int g = bx - 2368;
        int b = g >> 6;
        int t0 = (g & 63) * 32;
        sh[t] = dur[b * 256 + t];
        __syncthreads();
        for (int s = 128; s > 0; s >>= 1) {
            if (t < s) sh[t] += sh[t + s];
            __syncthreads();
        }
        int mel = sh[0];
        int w = t >> 6, lane = t & 63;
        f32x4 z4 = (f32x4){0.f, 0.f, 0.f, 0.f};
#pragma unroll
        for (int it = 0; it < 8; ++it) {
            int tt = t0 + it * 4 + w;
            if (tt >= mel)
                __builtin_nontemporal_store(z4,
                    (f32x4*)(out + ((size_t)(b * 2048 + tt)) * 256 + lane * 4));
        }
        if (t < 32) maskout[b * 2048 + t0 + t] = (t0 + t < mel) ? 0.f : 1.f;
    }
}

// ================= conv GEMM: 128x256 tile, 512 threads, BK=32 =================
// A staged ONCE (swizzled); B: 4-buffer depth-3 counted-vmcnt pipeline (one s_barrier/step).
// A-LDS: 130 rows x 512B; phys byte = r*512 + (c ^ ((r&7)<<4)); pre-swizzled global src.
// B-LDS: 256 rows x 64B; phys byte = c*64 + (kb ^ ((c&3)<<4)). 2 loads/thread/step (uniform).
__device__ __forceinline__ void stageA128(const unsigned short* __restrict__ A, int browPad,
                                          unsigned short* As, int tid) {
    for (int g = tid; g < 4160; g += 512) {
        int p = g * 16;
        int r = p >> 9;
        int c = (p & 511) ^ ((r & 7) << 4);
        __builtin_amdgcn_global_load_lds(
            (const __attribute__((address_space(1))) unsigned int*)((const char*)(A + (size_t)(browPad + r) * 256) + c),
            (__attribute__((address_space(3))) unsigned int*)((char*)As + p), 16, 0, 0);
    }
}

__device__ __forceinline__ void stageB128(const unsigned short* __restrict__ Bm, int kt,
                                          unsigned short* Bs, int tid) {
#pragma unroll
    for (int j = 0; j < 2; ++j) {
        int p = j * 8192 + tid * 16;
        int c = p >> 6;
        int kb = (p & 63) ^ ((c & 3) << 4);
        __builtin_amdgcn_global_load_lds(
            (const __attribute__((address_space(1))) unsigned int*)((const char*)(Bm + (size_t)c * KH + kt) + kb),
            (__attribute__((address_space(3))) unsigned int*)((char*)Bs + p), 16, 0, 0);
    }
}

__device__ __forceinline__ void compute128(const unsigned short* As, const unsigned short* Bs,
                                           int kt, int lane, int wr, int wc, f32x4 acc[4][4]) {
    const int rsel = lane & 15;
    const int lhi = lane >> 4;
    const int tap = kt >> 8;
    const int hcb = (kt & 255) * 2 + lhi * 16;
    bf16x8 af[4], bfr[4];
#pragma unroll
    for (int m = 0; m < 4; ++m) {
        int r = tap + wr * 64 + m * 16 + rsel;
        af[m] = *(const bf16x8*)((const char*)As + r * 512 + (hcb ^ ((r & 7) << 4)));
    }
#pragma unroll
    for (int n = 0; n < 4; ++n) {
        int c = wc * 64 + n * 16 + rsel;
        bfr[n] = *(const bf16x8*)((const char*)Bs + c * 64 + ((lhi * 16) ^ ((c & 3) << 4)));
    }
#pragma unroll
    for (int m = 0; m < 4; ++m)
#pragma unroll
        for (int n = 0; n < 4; ++n)
            acc[m][n] = __builtin_amdgcn_mfma_f32_16x16x32_bf16(af[m], bfr[n], acc[m][n], 0, 0, 0);
}

// K sweep: 4 B-buffers, depth-3 prefetch, counted vmcnt (never 0 in steady state),
// one raw barrier per step. Prologue: B0, A, B1, B2 issued.
// At step t outstanding = stages t,t+1,t+2 (6 loads): vmcnt(4) => stage t landed (FIFO).
// Restage target (t+3)&3 == (t-1)&3, last read at compute t-1, done before barrier t.
__device__ __forceinline__ void conv_kloop(const unsigned short* __restrict__ A,
                                           const unsigned short* __restrict__ Bm,
                                           int browPad, int lane, int wr, int wc, int tid,
                                           unsigned short* As, unsigned short (*Bs)[8192],
                                           f32x4 acc[4][4]) {
    stageB128(Bm, 0, Bs[0], tid);
    stageA128(A, browPad, As, tid);
    stageB128(Bm, 32, Bs[1], tid);
    stageB128(Bm, 64, Bs[2], tid);
#pragma unroll
    for (int t = 0; t < 24; ++t) {
        if (t <= 21)      asm volatile("s_waitcnt vmcnt(4)" ::: "memory");
        else if (t == 22) asm volatile("s_waitcnt vmcnt(2)" ::: "memory");
        else              asm volatile("s_waitcnt vmcnt(0)" ::: "memory");
        __builtin_amdgcn_s_barrier();
        __builtin_amdgcn_sched_barrier(0);
        if (t + 3 < 24)
            stageB128(Bm, (t + 3) * 32, Bs[(t + 3) & 3], tid);
        compute128(As, Bs[t & 3], t * 32, lane, wr, wc, acc);
    }
    __syncthreads();
}

// ================= conv1 + bias + relu + LN -> padded bf16 h =================
__global__ __launch_bounds__(512) void k_conv_ln1(
        const unsigned short* __restrict__ xplain, const unsigned short* __restrict__ xpplain,
        const unsigned short* __restrict__ bt,
        const float* __restrict__ b1, const float* __restrict__ g1, const float* __restrict__ be1,
        unsigned short* __restrict__ h0, unsigned short* __restrict__ h1, unsigned short* __restrict__ h2) {
    __shared__ unsigned short As[33280];     // 130 rows x 512B, swizzled
    __shared__ unsigned short Bs[4][8192];   // 256 x 64B, swizzled, 4-buf
    __shared__ float2 red[4][128];

    const int pred = blockIdx.y;
    const unsigned short* A  = (pred < 2) ? xplain : xpplain;
    const unsigned short* Bm = bt + (size_t)pred * 256 * KH;
    unsigned short* hout = (pred == 0) ? h0 : (pred == 1) ? h1 : h2;

    const int rowBase = blockIdx.x * 128;
    const int bb = rowBase >> 8;
    const int l0 = rowBase & 255;
    const int browPad = bb * PADL + l0;
    const int tid = threadIdx.x;
    const int lane = tid & 63;
    const int wv = tid >> 6;
    const int wr = wv >> 2, wc = wv & 3;
    const int rsel = lane & 15;
    const int lhi = lane >> 4;

    f32x4 acc[4][4];
#pragma unroll
    for (int m = 0; m < 4; ++m)
#pragma unroll
        for (int n = 0; n < 4; ++n) acc[m][n] = (f32x4){0.f, 0.f, 0.f, 0.f};

    conv_kloop(A, Bm, browPad, lane, wr, wc, tid, As, Bs, acc);

    float bcol[4], gcol[4], becol[4];
#pragma unroll
    for (int n = 0; n < 4; ++n) {
        int c = wc * 64 + n * 16 + rsel;
        bcol[n] = b1[pred * 256 + c];
        gcol[n] = g1[pred * 256 + c];
        becol[n] = be1[pred * 256 + c];
    }

#pragma unroll
    for (int m = 0; m < 4; ++m)
#pragma unroll
        for (int r = 0; r < 4; ++r) {
            float s = 0.f, s2 = 0.f;
#pragma unroll
            for (int n = 0; n < 4; ++n) {
                float v = fmaxf(acc[m][n][r] + bcol[n], 0.f);
                s += v; s2 += v * v;
            }
#pragma unroll
            for (int o = 1; o < 16; o <<= 1) { s += __shfl_xor(s, o); s2 += __shfl_xor(s2, o); }
            if (rsel == 0) red[wc][wr * 64 + m * 16 + lhi * 4 + r] = make_float2(s, s2);
        }
    __syncthreads();
    if (tid < 128) {
        float2 a0 = red[0][tid], a1 = red[1][tid], a2 = red[2][tid], a3 = red[3][tid];
        red[0][tid] = make_float2(a0.x + a1.x + a2.x + a3.x, a0.y + a1.y + a2.y + a3.y);
    }
    __syncthreads();

#pragma unroll
    for (int m = 0; m < 4; ++m)
#pragma unroll
        for (int r = 0; r < 4; ++r) {
            int rl = wr * 64 + m * 16 + lhi * 4 + r;
            float2 t = red[0][rl];
            float mean = t.x * (1.f / 256.f);
            float var = t.y * (1.f / 256.f) - mean * mean;
            float inv = rsqrtf(var + EPS_);
            int l = l0 + rl;
            size_t row = (size_t)bb * PADL + 1 + l;
#pragma unroll
            for (int n = 0; n < 4; ++n) {
                float v = fmaxf(acc[m][n][r] + bcol[n], 0.f);
                float h = (v - mean) * inv * gcol[n] + becol[n];
                int c = wc * 64 + n * 16 + rsel;
                hout[row * 256 + c] = f2bf(h);
                if (l == 0)   hout[((size_t)bb * PADL) * 256 + c] = 0;
                if (l == 255) hout[((size_t)bb * PADL + 257) * 256 + c] = 0;
            }
        }
}

// ================= conv2 + bias + relu + LN + dot(wl) + mask -> predictions =================
__global__ __launch_bounds__(512) void k_conv_ln2(
        const unsigned short* __restrict__ h0, const unsigned short* __restrict__ h1,
        const unsigned short* __restrict__ h2, const unsigned short* __restrict__ bt,
        const float* __restrict__ b2, const float* __restrict__ g2, const float* __restrict__ be2,
        const float* __restrict__ wl, const float* __restrict__ bl,
        const char* __restrict__ mask, float* __restrict__ outp) {
    __shared__ unsigned short As[33280];
    __shared__ unsigned short Bs[4][8192];
    __shared__ float2 red[4][128];
    __shared__ float  red2[4][128];

    const int pred = blockIdx.y;
    const unsigned short* A  = (pred == 0) ? h0 : (pred == 1) ? h1 : h2;
    const unsigned short* Bm = bt + (size_t)(768 + pred * 256) * KH;

    const int rowBase = blockIdx.x * 128;
    const int bb = rowBase >> 8;
    const int l0 = rowBase & 255;
    const int browPad = bb * PADL + l0;
    const int tid = threadIdx.x;
    const int lane = tid & 63;
    const int wv = tid >> 6;
    const int wr = wv >> 2, wc = wv & 3;
    const int rsel = lane & 15;
    const int lhi = lane >> 4;

    f32x4 acc[4][4];
#pragma unroll
    for (int m = 0; m < 4; ++m)
#pragma unroll
        for (int n = 0; n < 4; ++n) acc[m][n] = (f32x4){0.f, 0.f, 0.f, 0.f};

    conv_kloop(A, Bm, browPad, lane, wr, wc, tid, As, Bs, acc);

    float bcol[4], gcol[4], becol[4], wcol[4];
#pragma unroll
    for (int n = 0; n < 4; ++n) {
        int c = wc * 64 + n * 16 + rsel;
        bcol[n] = b2[pred * 256 + c];
        gcol[n] = g2[pred * 256 + c];
        becol[n] = be2[pred * 256 + c];
        wcol[n] = wl[pred * 256 + c];
    }

#pragma unroll
    for (int m = 0; m < 4; ++m)
#pragma unroll
        for (int r = 0; r < 4; ++r) {
            float s = 0.f, s2 = 0.f;
#pragma unroll
            for (int n = 0; n < 4; ++n) {
                float v = fmaxf(acc[m][n][r] + bcol[n], 0.f);
                s += v; s2 += v * v;
            }
#pragma unroll
            for (int o = 1; o < 16; o <<= 1) { s += __shfl_xor(s, o); s2 += __shfl_xor(s2, o); }
            if (rsel == 0) red[wc][wr * 64 + m * 16 + lhi * 4 + r] = make_float2(s, s2);
        }
    __syncthreads();
    if (tid < 128) {
        float2 a0 = red[0][tid], a1 = red[1][tid], a2 = red[2][tid], a3 = red[3][tid];
        red[0][tid] = make_float2(a0.x + a1.x + a2.x + a3.x, a0.y + a1.y + a2.y + a3.y);
    }
    __syncthreads();

#pragma unroll
    for (int m = 0; m < 4; ++m)
#pragma unroll
        for (int r = 0; r < 4; ++r) {
            int rl = wr * 64 + m * 16 + lhi * 4 + r;
            float2 t = red[0][rl];
            float mean = t.x * (1.f / 256.f);
            float var = t.y * (1.f / 256.f) - mean * mean;
            float inv = rsqrtf(var + EPS_);
            float d = 0.f;
#pragma unroll
            for (int n = 0; n < 4; ++n) {
                float v = fmaxf(acc[m][n][r] + bcol[n], 0.f);
                float h = (v - mean) * inv * gcol[n] + becol[n];
                d += h * wcol[n];
            }
#pragma unroll
            for (int o = 1; o < 16; o <<= 1) d += __shfl_xor(d, o);
            if (rsel == 0) red2[wc][rl] = d;
        }
    __syncthreads();
    if (tid < 128) {
        int p = rowBase + tid;
        float o = red2[0][tid] + red2[1][tid] + red2[2][tid] + red2[3][tid] + bl[pred];
        if (mask[p]) o = 0.f;
        outp[(size_t)pred * P_TOT + p] = o;
    }
}

extern "C" void kernel_launch(void* const* d_in, const int* in_sizes, int n_in,
                              void* d_out, int out_size, void* d_ws, size_t ws_size,
                              hipStream_t stream) {
    const float* x     = (const float*)d_in[0];
    const float* pt    = (const float*)d_in[1];
    const float* et    = (const float*)d_in[2];
    const float* w1    = (const float*)d_in[3];
    const float* b1    = (const float*)d_in[4];
    const float* g1    = (const float*)d_in[5];
    const float* be1   = (const float*)d_in[6];
    const float* w2    = (const float*)d_in[7];
    const float* b2    = (const float*)d_in[8];
    const float* g2    = (const float*)d_in[9];
    const float* be2   = (const float*)d_in[10];
    const float* wl    = (const float*)d_in[11];
    const float* bl    = (const float*)d_in[12];
    const float* pbins = (const float*)d_in[13];
    const float* ebins = (const float*)d_in[14];
    const float* pemb  = (const float*)d_in[15];
    const float* eemb  = (const float*)d_in[16];
    const char*  mask  = (const char*)d_in[17];
    const int*   dur   = (const int*)d_in[18];

    char* ws = (char*)d_ws;
    unsigned short* xplain  = (unsigned short*)(ws + 0);
    unsigned short* xpplain = (unsigned short*)(ws + 8388608);
    unsigned short* h0      = (unsigned short*)(ws + 16777216);
    unsigned short* h1      = (unsigned short*)(ws + 25165824);
    unsigned short* h2      = (unsigned short*)(ws + 33554432);
    unsigned short* btall   = (unsigned short*)(ws + 52428800);

    float* out        = (float*)d_out;
    float* out_pred   = out + 16777216;           // log_dur | pitch | energy (8192 each)
    float* out_mellen = out + 16801792;
    float* out_mask   = out + 16801824;

    hipLaunchKernelGGL(k_pre, dim3(4416), dim3(256), 0, stream,
                       x, pt, et, pbins, ebins, pemb, eemb, w1, w2, dur,
                       xplain, xpplain, btall, out, out_mask, out_mellen);

    hipLaunchKernelGGL(k_conv_ln1, dim3(64, 3), dim3(512), 0, stream,
                       xplain, xpplain, btall, b1, g1, be1, h0, h1, h2);

    hipLaunchKernelGGL(k_conv_ln2, dim3(64, 3), dim3(512), 0, stream,
                       h0, h1, h2, btall, b2, g2, be2, wl, bl, mask, out_pred);
}